// Round 1
// baseline (645.000 us; speedup 1.0000x reference)
//
#include <hip/hip_runtime.h>

// Problem constants (match reference)
#define N_NODES   4096
#define N_EDGES   65536
#define BATCH     8
#define EDGE_TYPES 2
#define UNITS     64

// ---------------------------------------------------------------------------
// Kernel 1: recover edge target indices from the dense one-hot [E, N] buffer.
// Density of nonzeros is 1/4096, so the hot path is a pure coalesced float4
// stream read at HBM bandwidth. Every edge row has exactly one 1.0, so idx[e]
// is fully (re)written every call -> deterministic, no reliance on ws state.
// ---------------------------------------------------------------------------
__global__ void extract_idx_kernel(const float4* __restrict__ tgt,
                                   int* __restrict__ idx) {
    const int total4 = N_EDGES * (N_NODES / 4);   // 67,108,864 float4s
    int i = blockIdx.x * blockDim.x + threadIdx.x;
    const int stride = gridDim.x * blockDim.x;
    for (; i < total4; i += stride) {
        float4 v = tgt[i];
        if (v.x != 0.f || v.y != 0.f || v.z != 0.f || v.w != 0.f) {
            int p = i << 2;                 // flat float index (fits in int: 2^28)
            int e = p >> 12;                // / N_NODES
            int c = p & (N_NODES - 1);      // % N_NODES
            int n;
            if      (v.x != 0.f) n = c;
            else if (v.y != 0.f) n = c + 1;
            else if (v.z != 0.f) n = c + 2;
            else                 n = c + 3;
            idx[e] = n;
        }
    }
}

// ---------------------------------------------------------------------------
// Kernel 2: zero the output (harness poisons it with 0xAA before timing).
// ---------------------------------------------------------------------------
__global__ void zero_out_kernel(float4* __restrict__ out) {
    const int total4 = BATCH * N_NODES * UNITS / 4;  // 524,288
    int i = blockIdx.x * blockDim.x + threadIdx.x;
    const int stride = gridDim.x * blockDim.x;
    for (; i < total4; i += stride) {
        out[i] = make_float4(0.f, 0.f, 0.f, 0.f);
    }
}

// ---------------------------------------------------------------------------
// Kernel 3: scatter-add. One thread per (b, e, u4): loads float4 msg for both
// edge types (coalesced: consecutive threads -> consecutive float4s within a
// 64-float edge row), fuses the t-sum, then 4 atomicAdds onto out[b,n,u].
// ---------------------------------------------------------------------------
__global__ void scatter_kernel(const float4* __restrict__ msgs,
                               const int* __restrict__ idx,
                               float* __restrict__ out) {
    int t = blockIdx.x * blockDim.x + threadIdx.x;  // 0 .. 8,388,607
    int u4 = t & 15;                 // which float4 of the 64-unit row
    int e  = (t >> 4) & (N_EDGES - 1);
    int b  = t >> 20;

    const float4 m0 = msgs[((b * EDGE_TYPES + 0) * N_EDGES + e) * (UNITS / 4) + u4];
    const float4 m1 = msgs[((b * EDGE_TYPES + 1) * N_EDGES + e) * (UNITS / 4) + u4];

    const int n = idx[e];
    float* dst = out + ((b * N_NODES + n) * UNITS) + (u4 << 2);
    atomicAdd(dst + 0, m0.x + m1.x);
    atomicAdd(dst + 1, m0.y + m1.y);
    atomicAdd(dst + 2, m0.z + m1.z);
    atomicAdd(dst + 3, m0.w + m1.w);
}

extern "C" void kernel_launch(void* const* d_in, const int* in_sizes, int n_in,
                              void* d_out, int out_size, void* d_ws, size_t ws_size,
                              hipStream_t stream) {
    const float4* msgs = (const float4*)d_in[0];   // [B, T, E, U] fp32
    const float4* tgt  = (const float4*)d_in[1];   // [E, N] fp32 one-hot
    float* out = (float*)d_out;                    // [B, 1, N, U] fp32
    int* idx = (int*)d_ws;                         // 65536 ints scratch

    // 1) recover indices (reads 1 GiB; dominant cost, pure streaming)
    extract_idx_kernel<<<2048, 256, 0, stream>>>(tgt, idx);

    // 2) zero output
    zero_out_kernel<<<2048, 256, 0, stream>>>((float4*)out);

    // 3) scatter-add messages (reads 256 MiB)
    const int total_threads = BATCH * N_EDGES * (UNITS / 4);  // 8,388,608
    scatter_kernel<<<total_threads / 256, 256, 0, stream>>>(msgs, idx, out);
}

// Round 2
// 257.725 us; speedup vs baseline: 2.5027x; 2.5027x over previous
//
#include <hip/hip_runtime.h>

// Problem constants (match reference)
#define N_NODES    4096
#define N_EDGES    65536
#define BATCH      8
#define EDGE_TYPES 2
#define UNITS      64

// Workspace layout (all int32):
//   idx   [N_EDGES]    : target node of each edge
//   cnt   [N_NODES]    : per-node degree
//   start [N_NODES+1]  : CSR row starts (exclusive prefix of cnt)
//   pos   [N_NODES]    : CSR fill cursors
//   csr   [N_EDGES]    : edge ids grouped by target node
#define WS_IDX   0
#define WS_CNT   (WS_IDX + N_EDGES)
#define WS_START (WS_CNT + N_NODES)
#define WS_POS   (WS_START + N_NODES + 1)
#define WS_CSR   (WS_POS + N_NODES)

// ---------------------------------------------------------------------------
// 1) zero the per-node counters (cnt, pos). 8192 ints.
// ---------------------------------------------------------------------------
__global__ void init_kernel(int* __restrict__ cnt, int* __restrict__ pos) {
    int i = blockIdx.x * blockDim.x + threadIdx.x;
    if (i < N_NODES) { cnt[i] = 0; pos[i] = 0; }
}

// ---------------------------------------------------------------------------
// 2) recover edge target indices from the dense one-hot [E, N] buffer and
//    count per-node degree. Pure coalesced float4 stream (1 GiB) — the HBM
//    floor of this problem. Nonzero density 1/4096 keeps the branch cold.
// ---------------------------------------------------------------------------
__global__ void extract_idx_kernel(const float4* __restrict__ tgt,
                                   int* __restrict__ idx,
                                   int* __restrict__ cnt) {
    const int total4 = N_EDGES * (N_NODES / 4);   // 67,108,864 float4s
    int i = blockIdx.x * blockDim.x + threadIdx.x;
    const int stride = gridDim.x * blockDim.x;
    for (; i < total4; i += stride) {
        float4 v = tgt[i];
        if (v.x != 0.f || v.y != 0.f || v.z != 0.f || v.w != 0.f) {
            int p = i << 2;                 // flat float index (2^28, fits int)
            int e = p >> 12;                // / N_NODES
            int c = p & (N_NODES - 1);      // % N_NODES
            int n;
            if      (v.x != 0.f) n = c;
            else if (v.y != 0.f) n = c + 1;
            else if (v.z != 0.f) n = c + 2;
            else                 n = c + 3;
            idx[e] = n;
            atomicAdd(&cnt[n], 1);
        }
    }
}

// ---------------------------------------------------------------------------
// 3) exclusive prefix scan over the 4096 counts -> start[0..4096].
//    Single block, 1024 threads, 4 elements/thread, shfl wave-scan.
// ---------------------------------------------------------------------------
__global__ void scan_kernel(const int* __restrict__ cnt, int* __restrict__ start) {
    __shared__ int wave_sums[16];
    const int t = threadIdx.x;          // 0..1023
    const int lane = t & 63;
    const int wid = t >> 6;             // 16 waves

    int4 c = ((const int4*)cnt)[t];
    const int local = c.x + c.y + c.z + c.w;

    // inclusive scan of per-thread sums within the wave
    int v = local;
    for (int off = 1; off < 64; off <<= 1) {
        int u = __shfl_up(v, off, 64);
        if (lane >= off) v += u;
    }
    if (lane == 63) wave_sums[wid] = v;
    __syncthreads();
    if (wid == 0 && lane < 16) {
        int ws = wave_sums[lane];
        for (int off = 1; off < 16; off <<= 1) {
            int u = __shfl_up(ws, off, 64);
            if (lane >= off) ws += u;
        }
        wave_sums[lane] = ws;           // inclusive wave totals
    }
    __syncthreads();

    const int wave_excl = (wid == 0) ? 0 : wave_sums[wid - 1];
    const int thread_excl = wave_excl + (v - local);

    int4 s;
    s.x = thread_excl;
    s.y = s.x + c.x;
    s.z = s.y + c.y;
    s.w = s.z + c.z;
    ((int4*)start)[t] = s;
    if (t == 1023) start[N_NODES] = s.w + c.w;   // total = N_EDGES
}

// ---------------------------------------------------------------------------
// 4) fill CSR: group edge ids by target node.
// ---------------------------------------------------------------------------
__global__ void fill_csr_kernel(const int* __restrict__ idx,
                                const int* __restrict__ start,
                                int* __restrict__ pos,
                                int* __restrict__ csr) {
    int e = blockIdx.x * blockDim.x + threadIdx.x;
    if (e < N_EDGES) {
        int n = idx[e];
        int p = atomicAdd(&pos[n], 1);
        csr[start[n] + p] = e;
    }
}

// ---------------------------------------------------------------------------
// 5) gather: thread per (b, n, u4). Sums both edge types over the node's
//    edge list; plain float4 store (no atomics, no output pre-zeroing).
//    16 consecutive threads read one contiguous 256 B msg row chunk.
// ---------------------------------------------------------------------------
__global__ void gather_kernel(const float4* __restrict__ msgs,
                              const int* __restrict__ csr,
                              const int* __restrict__ start,
                              float4* __restrict__ out) {
    const int t = blockIdx.x * blockDim.x + threadIdx.x;   // 0 .. 524,287
    const int u4 = t & 15;
    const int n  = (t >> 4) & (N_NODES - 1);
    const int b  = t >> 16;

    const int j0 = start[n];
    const int j1 = start[n + 1];

    const float4* m0 = msgs + (size_t)(b * EDGE_TYPES) * N_EDGES * (UNITS / 4);
    const float4* m1 = m0 + (size_t)N_EDGES * (UNITS / 4);

    float4 acc = make_float4(0.f, 0.f, 0.f, 0.f);
    for (int j = j0; j < j1; ++j) {
        const int e = csr[j];                 // broadcast across the 16 threads
        const float4 a = m0[e * (UNITS / 4) + u4];
        const float4 c = m1[e * (UNITS / 4) + u4];
        acc.x += a.x + c.x;
        acc.y += a.y + c.y;
        acc.z += a.z + c.z;
        acc.w += a.w + c.w;
    }
    out[t] = acc;   // t == (b*N_NODES + n)*16 + u4 exactly
}

extern "C" void kernel_launch(void* const* d_in, const int* in_sizes, int n_in,
                              void* d_out, int out_size, void* d_ws, size_t ws_size,
                              hipStream_t stream) {
    const float4* msgs = (const float4*)d_in[0];   // [B, T, E, U] fp32
    const float4* tgt  = (const float4*)d_in[1];   // [E, N] fp32 one-hot
    float4* out = (float4*)d_out;                  // [B, 1, N, U] fp32

    int* ws    = (int*)d_ws;
    int* idx   = ws + WS_IDX;
    int* cnt   = ws + WS_CNT;
    int* start = ws + WS_START;
    int* pos   = ws + WS_POS;
    int* csr   = ws + WS_CSR;

    // 1) zero counters
    init_kernel<<<(N_NODES + 255) / 256, 256, 0, stream>>>(cnt, pos);

    // 2) recover indices + per-node degree (reads 1 GiB, streaming)
    extract_idx_kernel<<<2048, 256, 0, stream>>>(tgt, idx, cnt);

    // 3) prefix scan -> CSR row starts
    scan_kernel<<<1, 1024, 0, stream>>>(cnt, start);

    // 4) group edges by node
    fill_csr_kernel<<<N_EDGES / 256, 256, 0, stream>>>(idx, start, pos, csr);

    // 5) gather + fused type-sum (reads 256 MiB, writes 8 MiB, no atomics)
    const int total_threads = BATCH * N_NODES * (UNITS / 4);  // 524,288
    gather_kernel<<<total_threads / 256, 256, 0, stream>>>(msgs, csr, start, out);
}